// Round 7
// baseline (284.351 us; speedup 1.0000x reference)
//
#include <hip/hip_runtime.h>
#include <hip/hip_cooperative_groups.h>

namespace cg = cooperative_groups;

typedef unsigned short u16;
typedef __bf16 bf16x8 __attribute__((ext_vector_type(8)));
typedef float f32x4 __attribute__((ext_vector_type(4)));

#define GLD_LDS(gptr, lptr) \
  __builtin_amdgcn_global_load_lds((const __attribute__((address_space(1))) void*)(gptr), \
                                   (__attribute__((address_space(3))) void*)(lptr), 16, 0, 0)

__device__ __forceinline__ u16 f2b(float f) {
  union { __bf16 h; u16 u; } v; v.h = (__bf16)f; return v.u;
}
__device__ __forceinline__ float elu1(float v) {
  return v > 0.f ? v : (__expf(v) - 1.f);
}

union SMem {
  float tbuf[64][65];                                  // 16.6 KB (converts)
  struct { alignas(16) u16 As[2][2048]; alignas(16) u16 Bs[2][4096]; } g;  // 24 KB (gemm)
};

// ---------------- convert one 64x64 transpose tile / x-copy tile ----------------
__device__ void convert_tile(SMem& sm, int b,
                             const float* __restrict__ W_in, const float* __restrict__ W1,
                             const float* __restrict__ W2, const float* __restrict__ x,
                             u16* __restrict__ o0, u16* __restrict__ o1,
                             u16* __restrict__ o2, u16* __restrict__ ox) {
  const int tid = threadIdx.x;
  if (b >= 1216) {  // x f32 -> bf16 straight copy
    const size_t base = (size_t)(b - 1216) * 2048 + (size_t)tid * 8;
    float4 v0 = *reinterpret_cast<const float4*>(x + base);
    float4 v1 = *reinterpret_cast<const float4*>(x + base + 4);
    ushort4 a, c;
    a.x = f2b(v0.x); a.y = f2b(v0.y); a.z = f2b(v0.z); a.w = f2b(v0.w);
    c.x = f2b(v1.x); c.y = f2b(v1.y); c.z = f2b(v1.z); c.w = f2b(v1.w);
    *reinterpret_cast<ushort4*>(ox + base) = a;
    *reinterpret_cast<ushort4*>(ox + base + 4) = c;
    return;
  }
  const float* src; u16* dst; int R, C, tr, tc; size_t zoff;
  if (b < 128) {
    src = W_in; dst = o0; R = 512; C = 1024; tr = b >> 4; tc = b & 15; zoff = 0;
  } else if (b < 1152) {
    int t = b - 128; int z = t >> 7, rem = t & 127;
    src = W1; dst = o1; R = 1024; C = 512; tr = rem >> 3; tc = rem & 7;
    zoff = (size_t)z * R * C;
  } else {
    int t = b - 1152; int z = t >> 3;
    src = W2; dst = o2; R = 512; C = 64; tr = t & 7; tc = 0;
    zoff = (size_t)z * R * C;
  }
  const float* sp = src + zoff + (size_t)(tr * 64) * C + tc * 64;
#pragma unroll
  for (int i = 0; i < 4; i++) {
    const int rr = (tid >> 4) + i * 16, f = tid & 15;
    float4 v = *reinterpret_cast<const float4*>(sp + (size_t)rr * C + f * 4);
    sm.tbuf[rr][f * 4 + 0] = v.x; sm.tbuf[rr][f * 4 + 1] = v.y;
    sm.tbuf[rr][f * 4 + 2] = v.z; sm.tbuf[rr][f * 4 + 3] = v.w;
  }
  __syncthreads();
  u16* dp = dst + zoff + (size_t)(tc * 64) * R + tr * 64;
#pragma unroll
  for (int i = 0; i < 4; i++) {
    const int u = tid + i * 256;
    const int c = u >> 4, rq = u & 15;
    ushort4 w;
    w.x = f2b(sm.tbuf[rq * 4 + 0][c]); w.y = f2b(sm.tbuf[rq * 4 + 1][c]);
    w.z = f2b(sm.tbuf[rq * 4 + 2][c]); w.w = f2b(sm.tbuf[rq * 4 + 3][c]);
    *reinterpret_cast<ushort4*>(dp + (size_t)c * R + rq * 4) = w;
  }
  __syncthreads();  // tbuf reused next loop iteration
}

// ---------------- routing (single block) ----------------
__device__ void route_body(const int* __restrict__ cat, int* __restrict__ list,
                           int* __restrict__ off) {
  __shared__ int cnt[8], cur[8], offs[9];
  const int tid = threadIdx.x;
  if (tid < 8) cnt[tid] = 0;
  __syncthreads();
  for (int i = tid; i < 8192; i += 256) atomicAdd(&cnt[cat[i]], 1);
  __syncthreads();
  if (tid == 0) {
    int s = 0;
    for (int e = 0; e < 8; e++) { offs[e] = s; s += cnt[e]; }
    offs[8] = s;
  }
  __syncthreads();
  if (tid < 8) cur[tid] = offs[tid];
  if (tid < 9) off[tid] = offs[tid];
  __syncthreads();
  for (int i = tid; i < 8192; i += 256) {
    int c = cat[i];
    list[atomicAdd(&cur[c], 1)] = i;
  }
}

// ---------------- R3-proven GEMM body: BM=64, BK=32, 4 waves, 2-buf prefetch ----------------
template<int LAYER, int BN, int K, int N>
__device__ void gemm_phase(SMem& sm,
                           const u16* __restrict__ A, const u16* __restrict__ Bw,
                           const float* __restrict__ bias,
                           const int* __restrict__ list, const int* __restrict__ off,
                           u16* __restrict__ outb, float* __restrict__ outf, int tile) {
  auto& As = sm.g.As;
  auto& Bs = sm.g.Bs;
  const int tid = threadIdx.x;
  const int wave = tid >> 6, lane = tid & 63;

  int e = 0, start = 0, cnt = 0, rowbase;
  int t = (LAYER == 1) ? (tile >> 3) : (LAYER == 2) ? (tile >> 2) : tile;
  if constexpr (LAYER == 1) {
    rowbase = t * 64;
  } else {
    int found = -1;
    for (e = 0; e < 8; e++) {
      int tiles = (off[e + 1] - off[e] + 63) >> 6;
      if (t < tiles) { found = e; break; }
      t -= tiles;
    }
    if (found < 0) return;
    start = off[e];
    cnt = off[e + 1] - start;
    rowbase = t * 64;
  }
  const int col0 = (LAYER == 1) ? (tile & 7) * 128 : (LAYER == 2) ? (tile & 3) * 128 : 0;

  const int srow = tid >> 2, skc = tid & 3;
  const int kxs = (skc ^ (srow & 3)) * 8;

  const u16* a_src;
  if constexpr (LAYER == 1) {
    a_src = A + (size_t)(rowbase + srow) * K + kxs;
  } else if constexpr (LAYER == 2) {
    int gr = list[start + min(rowbase + srow, cnt - 1)];
    a_src = A + (size_t)gr * K + kxs;
  } else {
    a_src = A + (size_t)(start + min(rowbase + srow, cnt - 1)) * K + kxs;
  }
  const u16* Bbase = Bw + (LAYER == 1 ? (size_t)0 : (size_t)e * N * K);
  const u16* b_src0 = Bbase + (size_t)(col0 + srow) * K + kxs;
  const u16* b_src1 = Bbase + (size_t)(col0 + 64 + srow) * K + kxs;

  const int wbase = wave * 512;

  constexpr int NR = BN / 32;
  const int wy = wave & 1, wx = wave >> 1;
  const int fr = lane & 15, kg = lane >> 4;
  const int kx = (kg ^ (fr & 3)) * 8;
  const int ar0 = (wy * 32 + fr) * 32 + kx;
  const int br0 = (wx * (BN / 2) + fr) * 32 + kx;

  f32x4 acc[2][NR] = {};

  constexpr int NK = K / 32;
  GLD_LDS(a_src, &As[0][wbase]);
  GLD_LDS(b_src0, &Bs[0][wbase]);
  if constexpr (BN == 128) GLD_LDS(b_src1, &Bs[0][2048 + wbase]);
  __syncthreads();
  for (int it = 0; it < NK; ++it) {
    const int cur = it & 1;
    if (it + 1 < NK) {
      const int nxt = cur ^ 1;
      const int kt = (it + 1) * 32;
      GLD_LDS(a_src + kt, &As[nxt][wbase]);
      GLD_LDS(b_src0 + kt, &Bs[nxt][wbase]);
      if constexpr (BN == 128) GLD_LDS(b_src1 + kt, &Bs[nxt][2048 + wbase]);
    }
    bf16x8 af[2], bfv[NR];
#pragma unroll
    for (int m = 0; m < 2; m++) af[m] = *(const bf16x8*)&As[cur][ar0 + m * 16 * 32];
#pragma unroll
    for (int n = 0; n < NR; n++) bfv[n] = *(const bf16x8*)&Bs[cur][br0 + n * 16 * 32];
#pragma unroll
    for (int m = 0; m < 2; m++)
#pragma unroll
      for (int n = 0; n < NR; n++)
        acc[m][n] = __builtin_amdgcn_mfma_f32_16x16x32_bf16(af[m], bfv[n], acc[m][n], 0, 0, 0);
    __syncthreads();
  }

#pragma unroll
  for (int n = 0; n < NR; n++) {
    const int col = col0 + wx * (BN / 2) + n * 16 + fr;
    const float bc = bias[(LAYER == 1 ? 0 : e * N) + col];
#pragma unroll
    for (int m = 0; m < 2; m++) {
      const int rloc = wy * 32 + m * 16 + kg * 4;
#pragma unroll
      for (int j = 0; j < 4; j++) {
        const float v = acc[m][n][j] + bc;
        if constexpr (LAYER == 1) {
          outb[(size_t)(rowbase + rloc + j) * N + col] = f2b(elu1(v));
        } else if constexpr (LAYER == 2) {
          const int slot = rowbase + rloc + j;
          if (slot < cnt) outb[(size_t)(start + slot) * N + col] = f2b(elu1(v));
        } else {
          const int slot = rowbase + rloc + j;
          if (slot < cnt) outf[(size_t)list[start + slot] * N + col] = v;
        }
      }
    }
  }
}

// ---------------- cooperative mega-kernel (grid-stride, any grid size) ----------------
__global__ __launch_bounds__(256, 4) void fused_all(
    const float* __restrict__ W_in, const float* __restrict__ W1,
    const float* __restrict__ W2, const float* __restrict__ x,
    const int* __restrict__ cat, const float* __restrict__ b_in,
    const float* __restrict__ b1, const float* __restrict__ b2,
    u16* __restrict__ wtin, u16* __restrict__ w1t, u16* __restrict__ w2t,
    u16* __restrict__ xb, u16* __restrict__ midb, u16* __restrict__ hb,
    int* __restrict__ list, int* __restrict__ off, float* __restrict__ out) {
  __shared__ SMem sm;
  const int bid = blockIdx.x;
  const int nb = gridDim.x;
  cg::grid_group grid = cg::this_grid();

  // phase 0: converts (blocks 0..nb-2 grid-stride) || routing (block nb-1)
  if (bid == nb - 1) {
    route_body(cat, list, off);
  } else {
    for (int b = bid; b < 3264; b += nb - 1)
      convert_tile(sm, b, W_in, W1, W2, x, wtin, w1t, w2t, xb);
  }
  grid.sync();

  // phase 1: L1  [8192,512] @ [512,1024] -> midb   (1024 tiles)
  for (int tile = bid; tile < 1024; tile += nb)
    gemm_phase<1, 128, 512, 1024>(sm, xb, wtin, b_in, nullptr, nullptr, midb, nullptr, tile);
  grid.sync();

  // phase 2: L2 grouped  [cnt_e,1024] @ [1024,512] -> hb  (<=544 tiles)
  for (int tile = bid; tile < 544; tile += nb)
    gemm_phase<2, 128, 1024, 512>(sm, midb, w1t, b1, list, off, hb, nullptr, tile);
  grid.sync();

  // phase 3: L3 grouped  [cnt_e,512] @ [512,64] -> out  (<=136 tiles)
  for (int tile = bid; tile < 136; tile += nb)
    gemm_phase<3, 64, 512, 64>(sm, hb, w2t, b2, list, off, nullptr, out, tile);
}

// ---------------- fallback wrappers (R3-style multi-launch) ----------------
__global__ __launch_bounds__(256) void k_wcvt_route(
    const float* __restrict__ W_in, const float* __restrict__ W1,
    const float* __restrict__ W2, const float* __restrict__ x,
    const int* __restrict__ cat,
    u16* __restrict__ o0, u16* __restrict__ o1, u16* __restrict__ o2,
    u16* __restrict__ ox, int* __restrict__ list, int* __restrict__ off) {
  __shared__ SMem sm;
  if (blockIdx.x == 3264) route_body(cat, list, off);
  else convert_tile(sm, blockIdx.x, W_in, W1, W2, x, o0, o1, o2, ox);
}

template<int LAYER, int BN, int K, int N>
__global__ __launch_bounds__(256, 4) void k_gemm(
    const u16* __restrict__ A, const u16* __restrict__ Bw,
    const float* __restrict__ bias,
    const int* __restrict__ list, const int* __restrict__ off,
    u16* __restrict__ outb, float* __restrict__ outf) {
  __shared__ SMem sm;
  gemm_phase<LAYER, BN, K, N>(sm, A, Bw, bias, list, off, outb, outf, blockIdx.x);
}

// ---------------- launch ----------------

extern "C" void kernel_launch(void* const* d_in, const int* in_sizes, int n_in,
                              void* d_out, int out_size, void* d_ws, size_t ws_size,
                              hipStream_t stream) {
  const float* x    = (const float*)d_in[0];
  const int*   cat  = (const int*)d_in[1];
  const float* W_in = (const float*)d_in[2];
  const float* b_in = (const float*)d_in[3];
  const float* W1   = (const float*)d_in[4];
  const float* b1   = (const float*)d_in[5];
  const float* W2   = (const float*)d_in[6];
  const float* b2   = (const float*)d_in[7];
  float* out = (float*)d_out;

  char* p = (char*)d_ws;
  u16* xb   = (u16*)p; p += (size_t)8192 * 512 * 2;
  u16* midb = (u16*)p; p += (size_t)8192 * 1024 * 2;
  u16* hb   = (u16*)p; p += (size_t)8192 * 512 * 2;
  u16* wtin = (u16*)p; p += (size_t)1024 * 512 * 2;
  u16* w1t  = (u16*)p; p += (size_t)8 * 512 * 1024 * 2;
  u16* w2t  = (u16*)p; p += (size_t)8 * 64 * 512 * 2;
  int* list = (int*)p; p += (size_t)8192 * 4;
  int* off  = (int*)p; p += 64;

  // --- try cooperative single-dispatch path ---
  int bpc = 0;
  hipError_t qerr = hipOccupancyMaxActiveBlocksPerMultiprocessor(&bpc, fused_all, 256, 0);
  if (qerr == hipSuccess && bpc > 0) {
    int nb = bpc * 256;           // 256 CUs on MI355X
    if (nb > 1024) nb = 1024;
    void* args[] = {
      (void*)&W_in, (void*)&W1, (void*)&W2, (void*)&x, (void*)&cat,
      (void*)&b_in, (void*)&b1, (void*)&b2,
      (void*)&wtin, (void*)&w1t, (void*)&w2t, (void*)&xb, (void*)&midb, (void*)&hb,
      (void*)&list, (void*)&off, (void*)&out
    };
    hipError_t lerr = hipLaunchCooperativeKernel((void*)fused_all, dim3(nb), dim3(256),
                                                 args, 0, stream);
    if (lerr == hipSuccess) return;
    (void)hipGetLastError();  // clear sticky state, fall through
  } else {
    (void)hipGetLastError();
  }

  // --- fallback: proven R3-structure multi-launch path ---
  k_wcvt_route<<<3265, 256, 0, stream>>>(W_in, W1, W2, x, cat, wtin, w1t, w2t, xb, list, off);
  k_gemm<1, 128, 512, 1024><<<1024, 256, 0, stream>>>(xb, wtin, b_in, nullptr, nullptr, midb, nullptr);
  k_gemm<2, 128, 1024, 512><<<544, 256, 0, stream>>>(midb, w1t, b1, list, off, hb, nullptr);
  k_gemm<3, 64, 512, 64><<<136, 256, 0, stream>>>(hb, w2t, b2, list, off, nullptr, out);
}

// Round 9
// 70.583 us; speedup vs baseline: 4.0286x; 4.0286x over previous
//
#include <hip/hip_runtime.h>

typedef unsigned short u16;
typedef __bf16 bf16x8 __attribute__((ext_vector_type(8)));
typedef float f32x4 __attribute__((ext_vector_type(4)));

#define GLD_LDS(gptr, lptr) \
  __builtin_amdgcn_global_load_lds((const __attribute__((address_space(1))) void*)(gptr), \
                                   (__attribute__((address_space(3))) void*)(lptr), 16, 0, 0)

__device__ __forceinline__ u16 f2b(float f) {
  union { __bf16 h; u16 u; } v; v.h = (__bf16)f; return v.u;
}
__device__ __forceinline__ float elu1(float v) {
  return v > 0.f ? v : (__expf(v) - 1.f);
}

// ---------------- routing, stage 1: per-chunk histogram (64 chunks x 128 samples) ----------
__device__ void hist_body(int rb, const int* __restrict__ cat, int* __restrict__ cnts) {
  __shared__ int c8[8];
  const int tid = threadIdx.x;
  if (tid < 8) c8[tid] = 0;
  __syncthreads();
  if (tid < 128) atomicAdd(&c8[cat[rb * 128 + tid]], 1);
  __syncthreads();
  if (tid < 8) cnts[rb * 8 + tid] = c8[tid];
}

// ---------------- routing, stage 2: independent prefix + scatter (riding L1 dispatch) -------
__device__ void scatter_body(int rb, const int* __restrict__ cat,
                             const int* __restrict__ cnts,
                             int* __restrict__ list, int* __restrict__ off) {
  __shared__ int lc[512];       // cnts[64][8]
  __shared__ int lcur[8];
  __shared__ int starts[8];
  const int tid = threadIdx.x;
  lc[tid] = cnts[tid];          // FIX(R8 crash): 256 threads must load 512 entries;
  lc[tid + 256] = cnts[tid + 256];  // upper half was uninitialized -> wild list indices
  if (tid < 8) lcur[tid] = 0;
  __syncthreads();
  if (tid < 8) {
    const int c = tid;
    int base = 0;                         // off[c] = total count of cats < c
    for (int cc = 0; cc < c; cc++) {
      int s = 0;
      for (int b = 0; b < 64; b++) s += lc[b * 8 + cc];
      base += s;
    }
    int pre = 0;                          // this chunk's offset within cat c
    for (int b = 0; b < rb; b++) pre += lc[b * 8 + c];
    starts[c] = base + pre;
    if (rb == 0) {
      off[c] = base;
      if (c == 7) {
        int s = 0;
        for (int b = 0; b < 64; b++) s += lc[b * 8 + 7];
        off[8] = base + s;
      }
    }
  }
  __syncthreads();
  if (tid < 128) {
    const int idx = rb * 128 + tid;
    const int c = cat[idx];
    const int r = atomicAdd(&lcur[c], 1);
    list[starts[c] + r] = idx;
  }
}

// ---------------- fused convert + hist kernel ----------------
// blocks [0,128):    W_in [512][1024] f32 -> o0 [1024][512] bf16
// blocks [128,1152): W1 [8][1024][512]    -> o1 [8][512][1024]
// blocks [1152,1216):W2 [8][512][64]      -> o2 [8][64][512]
// blocks [1216,3264): x f32 -> bf16 copy
// blocks [3264,3328): routing histogram
__global__ __launch_bounds__(256) void wcvt(const float* __restrict__ W_in,
                                            const float* __restrict__ W1,
                                            const float* __restrict__ W2,
                                            const float* __restrict__ x,
                                            const int* __restrict__ cat,
                                            u16* __restrict__ o0, u16* __restrict__ o1,
                                            u16* __restrict__ o2, u16* __restrict__ ox,
                                            int* __restrict__ cnts) {
  const int bid = blockIdx.x, tid = threadIdx.x;
  if (bid >= 3264) {
    hist_body(bid - 3264, cat, cnts);
    return;
  }
  if (bid >= 1216) {
    const size_t base = (size_t)(bid - 1216) * 2048 + (size_t)tid * 8;
    float4 v0 = *reinterpret_cast<const float4*>(x + base);
    float4 v1 = *reinterpret_cast<const float4*>(x + base + 4);
    ushort4 a, b;
    a.x = f2b(v0.x); a.y = f2b(v0.y); a.z = f2b(v0.z); a.w = f2b(v0.w);
    b.x = f2b(v1.x); b.y = f2b(v1.y); b.z = f2b(v1.z); b.w = f2b(v1.w);
    *reinterpret_cast<ushort4*>(ox + base) = a;
    *reinterpret_cast<ushort4*>(ox + base + 4) = b;
    return;
  }
  const float* src; u16* dst; int R, C, tr, tc; size_t zoff;
  if (bid < 128) {
    src = W_in; dst = o0; R = 512; C = 1024; tr = bid >> 4; tc = bid & 15; zoff = 0;
  } else if (bid < 1152) {
    int t = bid - 128; int z = t >> 7, rem = t & 127;
    src = W1; dst = o1; R = 1024; C = 512; tr = rem >> 3; tc = rem & 7;
    zoff = (size_t)z * R * C;
  } else {
    int t = bid - 1152; int z = t >> 3;
    src = W2; dst = o2; R = 512; C = 64; tr = t & 7; tc = 0;
    zoff = (size_t)z * R * C;
  }
  __shared__ float tbuf[64][65];
  const float* sp = src + zoff + (size_t)(tr * 64) * C + tc * 64;
#pragma unroll
  for (int i = 0; i < 4; i++) {
    const int rr = (tid >> 4) + i * 16, f = tid & 15;
    float4 v = *reinterpret_cast<const float4*>(sp + (size_t)rr * C + f * 4);
    tbuf[rr][f * 4 + 0] = v.x; tbuf[rr][f * 4 + 1] = v.y;
    tbuf[rr][f * 4 + 2] = v.z; tbuf[rr][f * 4 + 3] = v.w;
  }
  __syncthreads();
  u16* dp = dst + zoff + (size_t)(tc * 64) * R + tr * 64;
#pragma unroll
  for (int i = 0; i < 4; i++) {
    const int u = tid + i * 256;
    const int c = u >> 4, rq = u & 15;
    ushort4 w;
    w.x = f2b(tbuf[rq * 4 + 0][c]); w.y = f2b(tbuf[rq * 4 + 1][c]);
    w.z = f2b(tbuf[rq * 4 + 2][c]); w.w = f2b(tbuf[rq * 4 + 3][c]);
    *reinterpret_cast<ushort4*>(dp + (size_t)c * R + rq * 4) = w;
  }
}

// ---------------- unified pipelined GEMM (R3-proven: BM=64, BK=32, 2-buf prefetch) ----------
// LAYER 1 also carries the 64 scatter blocks on blockIdx.y == 8.

template<int LAYER, int BN, int K, int N>
__global__ __launch_bounds__(256, 4) void gemm_t(
    const u16* __restrict__ A, const u16* __restrict__ Bw,
    const float* __restrict__ bias,
    const int* __restrict__ list, const int* __restrict__ off,
    u16* __restrict__ outb, float* __restrict__ outf,
    const int* __restrict__ cat, const int* __restrict__ cnts,
    int* __restrict__ wlist, int* __restrict__ woff) {
  __shared__ alignas(16) u16 As[2][64 * 32];
  __shared__ alignas(16) u16 Bs[2][BN * 32];

  if constexpr (LAYER == 1) {
    if (blockIdx.y == 8) {                 // routing scatter row
      if (blockIdx.x < 64) scatter_body(blockIdx.x, cat, cnts, wlist, woff);
      return;
    }
  }

  const int tid = threadIdx.x;
  const int wave = tid >> 6, lane = tid & 63;

  int e = 0, start = 0, cnt = 0, rowbase;
  if constexpr (LAYER == 1) {
    rowbase = blockIdx.x * 64;
  } else {
    int t = blockIdx.x;
    int found = -1;
    for (e = 0; e < 8; e++) {
      int tiles = (off[e + 1] - off[e] + 63) >> 6;
      if (t < tiles) { found = e; break; }
      t -= tiles;
    }
    if (found < 0) return;
    start = off[e];
    cnt = off[e + 1] - start;
    rowbase = t * 64;
  }
  const int col0 = blockIdx.y * BN;

  const int srow = tid >> 2, skc = tid & 3;
  const int kxs = (skc ^ (srow & 3)) * 8;

  const u16* a_src;
  if constexpr (LAYER == 1) {
    a_src = A + (size_t)(rowbase + srow) * K + kxs;
  } else if constexpr (LAYER == 2) {
    int gr = list[start + min(rowbase + srow, cnt - 1)];
    a_src = A + (size_t)gr * K + kxs;
  } else {
    a_src = A + (size_t)(start + min(rowbase + srow, cnt - 1)) * K + kxs;
  }
  const u16* Bbase = Bw + (LAYER == 1 ? (size_t)0 : (size_t)e * N * K);
  const u16* b_src0 = Bbase + (size_t)(col0 + srow) * K + kxs;
  const u16* b_src1 = Bbase + (size_t)(col0 + 64 + srow) * K + kxs;

  const int wbase = wave * 512;

  constexpr int NR = BN / 32;
  const int wy = wave & 1, wx = wave >> 1;
  const int fr = lane & 15, kg = lane >> 4;
  const int kx = (kg ^ (fr & 3)) * 8;
  const int ar0 = (wy * 32 + fr) * 32 + kx;
  const int br0 = (wx * (BN / 2) + fr) * 32 + kx;

  f32x4 acc[2][NR] = {};

  constexpr int NK = K / 32;
  GLD_LDS(a_src, &As[0][wbase]);
  GLD_LDS(b_src0, &Bs[0][wbase]);
  if constexpr (BN == 128) GLD_LDS(b_src1, &Bs[0][2048 + wbase]);
  __syncthreads();
  for (int it = 0; it < NK; ++it) {
    const int cur = it & 1;
    if (it + 1 < NK) {
      const int nxt = cur ^ 1;
      const int kt = (it + 1) * 32;
      GLD_LDS(a_src + kt, &As[nxt][wbase]);
      GLD_LDS(b_src0 + kt, &Bs[nxt][wbase]);
      if constexpr (BN == 128) GLD_LDS(b_src1 + kt, &Bs[nxt][2048 + wbase]);
    }
    bf16x8 af[2], bfv[NR];
#pragma unroll
    for (int m = 0; m < 2; m++) af[m] = *(const bf16x8*)&As[cur][ar0 + m * 16 * 32];
#pragma unroll
    for (int n = 0; n < NR; n++) bfv[n] = *(const bf16x8*)&Bs[cur][br0 + n * 16 * 32];
#pragma unroll
    for (int m = 0; m < 2; m++)
#pragma unroll
      for (int n = 0; n < NR; n++)
        acc[m][n] = __builtin_amdgcn_mfma_f32_16x16x32_bf16(af[m], bfv[n], acc[m][n], 0, 0, 0);
    __syncthreads();
  }

#pragma unroll
  for (int n = 0; n < NR; n++) {
    const int col = col0 + wx * (BN / 2) + n * 16 + fr;
    const float bc = bias[(LAYER == 1 ? 0 : e * N) + col];
#pragma unroll
    for (int m = 0; m < 2; m++) {
      const int rloc = wy * 32 + m * 16 + kg * 4;
#pragma unroll
      for (int j = 0; j < 4; j++) {
        const float v = acc[m][n][j] + bc;
        if constexpr (LAYER == 1) {
          outb[(size_t)(rowbase + rloc + j) * N + col] = f2b(elu1(v));
        } else if constexpr (LAYER == 2) {
          const int slot = rowbase + rloc + j;
          if (slot < cnt) outb[(size_t)(start + slot) * N + col] = f2b(elu1(v));
        } else {
          const int slot = rowbase + rloc + j;
          if (slot < cnt) outf[(size_t)list[start + slot] * N + col] = v;
        }
      }
    }
  }
}

// ---------------- launch ----------------

extern "C" void kernel_launch(void* const* d_in, const int* in_sizes, int n_in,
                              void* d_out, int out_size, void* d_ws, size_t ws_size,
                              hipStream_t stream) {
  const float* x    = (const float*)d_in[0];
  const int*   cat  = (const int*)d_in[1];
  const float* W_in = (const float*)d_in[2];
  const float* b_in = (const float*)d_in[3];
  const float* W1   = (const float*)d_in[4];
  const float* b1   = (const float*)d_in[5];
  const float* W2   = (const float*)d_in[6];
  const float* b2   = (const float*)d_in[7];
  float* out = (float*)d_out;

  char* p = (char*)d_ws;
  u16* xb   = (u16*)p; p += (size_t)8192 * 512 * 2;    // 8 MB
  u16* midb = (u16*)p; p += (size_t)8192 * 1024 * 2;   // 16 MB
  u16* hb   = (u16*)p; p += (size_t)8192 * 512 * 2;    // 8 MB
  u16* wtin = (u16*)p; p += (size_t)1024 * 512 * 2;    // 1 MB
  u16* w1t  = (u16*)p; p += (size_t)8 * 512 * 1024 * 2;// 8 MB
  u16* w2t  = (u16*)p; p += (size_t)8 * 64 * 512 * 2;  // 0.5 MB
  int* list = (int*)p; p += (size_t)8192 * 4;          // 32 KB
  int* off  = (int*)p; p += 64;
  int* cnts = (int*)p; p += 64 * 8 * 4;

  // conversions + routing histogram in one launch
  wcvt<<<3328, 256, 0, stream>>>(W_in, W1, W2, x, cat, wtin, w1t, w2t, xb, cnts);

  // layer 1 (+ routing scatter on y==8): [8192,512] @ [512,1024] -> midb
  gemm_t<1, 128, 512, 1024><<<dim3(128, 9), 256, 0, stream>>>(
      xb, wtin, b_in, nullptr, nullptr, midb, nullptr, cat, cnts, list, off);
  // layer 2 grouped: [cnt_e,1024] @ [1024,512] -> hb (compact)
  gemm_t<2, 128, 1024, 512><<<dim3(136, 4), 256, 0, stream>>>(
      midb, w1t, b1, list, off, hb, nullptr, nullptr, nullptr, nullptr, nullptr);
  // layer 3 grouped: [cnt_e,512] @ [512,64] -> out (scattered)
  gemm_t<3, 64, 512, 64><<<dim3(136, 1), 256, 0, stream>>>(
      hb, w2t, b2, list, off, nullptr, out, nullptr, nullptr, nullptr, nullptr);
}

// Round 10
// 66.815 us; speedup vs baseline: 4.2558x; 1.0564x over previous
//
#include <hip/hip_runtime.h>

typedef unsigned short u16;
typedef unsigned int u32;
typedef __bf16 bf16x8 __attribute__((ext_vector_type(8)));
typedef float f32x4 __attribute__((ext_vector_type(4)));

#define GLD_LDS(gptr, lptr) \
  __builtin_amdgcn_global_load_lds((const __attribute__((address_space(1))) void*)(gptr), \
                                   (__attribute__((address_space(3))) void*)(lptr), 16, 0, 0)

__device__ __forceinline__ u16 f2b(float f) {
  union { __bf16 h; u16 u; } v; v.h = (__bf16)f; return v.u;
}
__device__ __forceinline__ float elu1(float v) {
  return v > 0.f ? v : (__expf(v) - 1.f);
}

// ---------------- 64x64 transpose-convert tile (f32 [R][C] -> bf16 [C][R]) ----------------
__device__ void transpose_tile(float (*tbuf)[65], const float* __restrict__ src,
                               u16* __restrict__ dst, int R, int C, int tr, int tc,
                               size_t zoff) {
  const int tid = threadIdx.x;
  const float* sp = src + zoff + (size_t)(tr * 64) * C + tc * 64;
#pragma unroll
  for (int i = 0; i < 4; i++) {
    const int rr = (tid >> 4) + i * 16, f = tid & 15;
    float4 v = *reinterpret_cast<const float4*>(sp + (size_t)rr * C + f * 4);
    tbuf[rr][f * 4 + 0] = v.x; tbuf[rr][f * 4 + 1] = v.y;
    tbuf[rr][f * 4 + 2] = v.z; tbuf[rr][f * 4 + 3] = v.w;
  }
  __syncthreads();
  u16* dp = dst + zoff + (size_t)(tc * 64) * R + tr * 64;
#pragma unroll
  for (int i = 0; i < 4; i++) {
    const int u = tid + i * 256;
    const int c = u >> 4, rq = u & 15;
    ushort4 w;
    w.x = f2b(tbuf[rq * 4 + 0][c]); w.y = f2b(tbuf[rq * 4 + 1][c]);
    w.z = f2b(tbuf[rq * 4 + 2][c]); w.w = f2b(tbuf[rq * 4 + 3][c]);
    *reinterpret_cast<ushort4*>(dp + (size_t)c * R + rq * 4) = w;
  }
}

// ---------------- routing, stage 1: per-chunk histogram (64 chunks x 128 samples) ----------
__device__ void hist_body(int rb, const int* __restrict__ cat, int* __restrict__ cnts) {
  __shared__ int c8[8];
  const int tid = threadIdx.x;
  if (tid < 8) c8[tid] = 0;
  __syncthreads();
  if (tid < 128) atomicAdd(&c8[cat[rb * 128 + tid]], 1);
  __syncthreads();
  if (tid < 8) cnts[rb * 8 + tid] = c8[tid];
}

// ---------------- routing, stage 2: independent prefix + scatter -------------------------
__device__ void scatter_body(int rb, const int* __restrict__ cat,
                             const int* __restrict__ cnts,
                             int* __restrict__ list, int* __restrict__ off) {
  __shared__ int lc[512];       // cnts[64][8]
  __shared__ int lcur[8];
  __shared__ int starts[8];
  const int tid = threadIdx.x;
  lc[tid] = cnts[tid];
  lc[tid + 256] = cnts[tid + 256];
  if (tid < 8) lcur[tid] = 0;
  __syncthreads();
  if (tid < 8) {
    const int c = tid;
    int base = 0;
    for (int cc = 0; cc < c; cc++) {
      int s = 0;
      for (int b = 0; b < 64; b++) s += lc[b * 8 + cc];
      base += s;
    }
    int pre = 0;
    for (int b = 0; b < rb; b++) pre += lc[b * 8 + c];
    starts[c] = base + pre;
    if (rb == 0) {
      off[c] = base;
      if (c == 7) {
        int s = 0;
        for (int b = 0; b < 64; b++) s += lc[b * 8 + 7];
        off[8] = base + s;
      }
    }
  }
  __syncthreads();
  if (tid < 128) {
    const int idx = rb * 128 + tid;
    const int c = cat[idx];
    const int r = atomicAdd(&lcur[c], 1);
    list[starts[c] + r] = idx;
  }
}

// ---------------- small front kernel: W_in transpose + routing histogram -------------------
// blocks [0,128): W_in [512][1024] -> wtin [1024][512];  [128,192): histogram
__global__ __launch_bounds__(256) void wsmall(const float* __restrict__ W_in,
                                              const int* __restrict__ cat,
                                              u16* __restrict__ o0, int* __restrict__ cnts) {
  __shared__ float tbuf[64][65];
  if (blockIdx.x >= 128) { hist_body(blockIdx.x - 128, cat, cnts); return; }
  transpose_tile(tbuf, W_in, o0, 512, 1024, blockIdx.x >> 4, blockIdx.x & 15, 0);
}

// ---------------- unified pipelined GEMM (R3-proven loop: BM=64, BK=32, 2-buf prefetch) ----
// LAYER 1: A = x (f32, reg-staged with inline cvt), dense rows, bf16 out + ELU.
//          extra blockIdx.y rows: y==8 scatter, y==9..16 W1 transpose, y==17 W2 transpose.
// LAYER 2: rows gathered via list (bf16 via global_load_lds), compact bf16 out + ELU.
// LAYER 3: compact rows, f32 out scattered via list, no activation.

template<int LAYER, int BN, int K, int N>
__global__ __launch_bounds__(256, 4) void gemm_t(
    const float* __restrict__ Xf, const u16* __restrict__ A,
    const u16* __restrict__ Bw, const float* __restrict__ bias,
    const int* __restrict__ list, const int* __restrict__ off,
    u16* __restrict__ outb, float* __restrict__ outf,
    const int* __restrict__ cat, const int* __restrict__ cnts,
    int* __restrict__ wlist, int* __restrict__ woff,
    const float* __restrict__ Wc1, const float* __restrict__ Wc2,
    u16* __restrict__ o1, u16* __restrict__ o2) {
  struct GBuf { alignas(16) u16 As[2][2048]; alignas(16) u16 Bs[2][BN * 32]; };
  __shared__ union SM { GBuf g; float tbuf[64][65]; } sm;

  const int tid = threadIdx.x;

  if constexpr (LAYER == 1) {
    if (blockIdx.y == 8) {                 // routing scatter
      if (blockIdx.x < 64) scatter_body(blockIdx.x, cat, cnts, wlist, woff);
      return;
    }
    if (blockIdx.y >= 9) {                 // weight converts (overlap with L1 gemm)
      if (blockIdx.y <= 16) {
        const int t = (blockIdx.y - 9) * 128 + blockIdx.x;   // 0..1023
        const int z = t >> 7, rem = t & 127;
        transpose_tile(sm.tbuf, Wc1, o1, 1024, 512, rem >> 3, rem & 7,
                       (size_t)z * 1024 * 512);
      } else if (blockIdx.x < 64) {
        const int t = blockIdx.x, z = t >> 3;
        transpose_tile(sm.tbuf, Wc2, o2, 512, 64, t & 7, 0, (size_t)z * 512 * 64);
      }
      return;
    }
  }

  const int wave = tid >> 6, lane = tid & 63;

  int e = 0, start = 0, cnt = 0, rowbase;
  if constexpr (LAYER == 1) {
    rowbase = blockIdx.x * 64;
  } else {
    int t = blockIdx.x;
    int found = -1;
    for (e = 0; e < 8; e++) {
      int tiles = (off[e + 1] - off[e] + 63) >> 6;
      if (t < tiles) { found = e; break; }
      t -= tiles;
    }
    if (found < 0) return;
    start = off[e];
    cnt = off[e + 1] - start;
    rowbase = t * 64;
  }
  const int col0 = blockIdx.y * BN;

  const int srow = tid >> 2, skc = tid & 3;
  const int kxs = (skc ^ (srow & 3)) * 8;

  const float* ax = nullptr;
  const u16* a_src = nullptr;
  if constexpr (LAYER == 1) {
    ax = Xf + (size_t)(rowbase + srow) * K + kxs;
  } else if constexpr (LAYER == 2) {
    int gr = list[start + min(rowbase + srow, cnt - 1)];
    a_src = A + (size_t)gr * K + kxs;
  } else {
    a_src = A + (size_t)(start + min(rowbase + srow, cnt - 1)) * K + kxs;
  }
  const u16* Bbase = Bw + (LAYER == 1 ? (size_t)0 : (size_t)e * N * K);
  const u16* b_src0 = Bbase + (size_t)(col0 + srow) * K + kxs;
  const u16* b_src1 = Bbase + (size_t)(col0 + 64 + srow) * K + kxs;

  const int wbase = wave * 512;

  constexpr int NR = BN / 32;
  const int wy = wave & 1, wx = wave >> 1;
  const int fr = lane & 15, kg = lane >> 4;
  const int kx = (kg ^ (fr & 3)) * 8;
  const int ar0 = (wy * 32 + fr) * 32 + kx;
  const int br0 = (wx * (BN / 2) + fr) * 32 + kx;

  f32x4 acc[2][NR] = {};

  float4 va0, va1;                          // L1 in-flight A (f32)
  auto LOAD_A1 = [&](int t) {
    va0 = *reinterpret_cast<const float4*>(ax + t * 32);
    va1 = *reinterpret_cast<const float4*>(ax + t * 32 + 4);
  };
  auto WRITE_A1 = [&](int buf) {
    uint4 w;
    w.x = (u32)f2b(va0.x) | ((u32)f2b(va0.y) << 16);
    w.y = (u32)f2b(va0.z) | ((u32)f2b(va0.w) << 16);
    w.z = (u32)f2b(va1.x) | ((u32)f2b(va1.y) << 16);
    w.w = (u32)f2b(va1.z) | ((u32)f2b(va1.w) << 16);
    *reinterpret_cast<uint4*>(&sm.g.As[buf][srow * 32 + skc * 8]) = w;
  };
  auto COMPUTE = [&](int buf) {
    bf16x8 af[2], bfv[NR];
#pragma unroll
    for (int m = 0; m < 2; m++) af[m] = *(const bf16x8*)&sm.g.As[buf][ar0 + m * 16 * 32];
#pragma unroll
    for (int n = 0; n < NR; n++) bfv[n] = *(const bf16x8*)&sm.g.Bs[buf][br0 + n * 16 * 32];
#pragma unroll
    for (int m = 0; m < 2; m++)
#pragma unroll
      for (int n = 0; n < NR; n++)
        acc[m][n] = __builtin_amdgcn_mfma_f32_16x16x32_bf16(af[m], bfv[n], acc[m][n], 0, 0, 0);
  };

  constexpr int NK = K / 32;
  if constexpr (LAYER == 1) LOAD_A1(0);
  else GLD_LDS(a_src, &sm.g.As[0][wbase]);
  GLD_LDS(b_src0, &sm.g.Bs[0][wbase]);
  if constexpr (BN == 128) GLD_LDS(b_src1, &sm.g.Bs[0][2048 + wbase]);
  if constexpr (LAYER == 1) WRITE_A1(0);
  __syncthreads();

  for (int it = 0; it < NK; ++it) {
    const int cur = it & 1;
    const int nxt = cur ^ 1;
    if (it + 1 < NK) {       // issue next-tile loads (stay in flight across compute)
      const int kt = (it + 1) * 32;
      if constexpr (LAYER == 1) LOAD_A1(it + 1);
      else GLD_LDS(a_src + kt, &sm.g.As[nxt][wbase]);
      GLD_LDS(b_src0 + kt, &sm.g.Bs[nxt][wbase]);
      if constexpr (BN == 128) GLD_LDS(b_src1 + kt, &sm.g.Bs[nxt][2048 + wbase]);
    }
    COMPUTE(cur);
    if constexpr (LAYER == 1) { if (it + 1 < NK) WRITE_A1(nxt); }  // cvt+write after MFMAs
    __syncthreads();
  }

#pragma unroll
  for (int n = 0; n < NR; n++) {
    const int col = col0 + wx * (BN / 2) + n * 16 + fr;
    const float bc = bias[(LAYER == 1 ? 0 : e * N) + col];
#pragma unroll
    for (int m = 0; m < 2; m++) {
      const int rloc = wy * 32 + m * 16 + kg * 4;
#pragma unroll
      for (int j = 0; j < 4; j++) {
        const float v = acc[m][n][j] + bc;
        if constexpr (LAYER == 1) {
          outb[(size_t)(rowbase + rloc + j) * N + col] = f2b(elu1(v));
        } else if constexpr (LAYER == 2) {
          const int slot = rowbase + rloc + j;
          if (slot < cnt) outb[(size_t)(start + slot) * N + col] = f2b(elu1(v));
        } else {
          const int slot = rowbase + rloc + j;
          if (slot < cnt) outf[(size_t)list[start + slot] * N + col] = v;
        }
      }
    }
  }
}

// ---------------- launch ----------------

extern "C" void kernel_launch(void* const* d_in, const int* in_sizes, int n_in,
                              void* d_out, int out_size, void* d_ws, size_t ws_size,
                              hipStream_t stream) {
  const float* x    = (const float*)d_in[0];
  const int*   cat  = (const int*)d_in[1];
  const float* W_in = (const float*)d_in[2];
  const float* b_in = (const float*)d_in[3];
  const float* W1   = (const float*)d_in[4];
  const float* b1   = (const float*)d_in[5];
  const float* W2   = (const float*)d_in[6];
  const float* b2   = (const float*)d_in[7];
  float* out = (float*)d_out;

  char* p = (char*)d_ws;
  u16* midb = (u16*)p; p += (size_t)8192 * 1024 * 2;   // 16 MB
  u16* hb   = (u16*)p; p += (size_t)8192 * 512 * 2;    // 8 MB
  u16* wtin = (u16*)p; p += (size_t)1024 * 512 * 2;    // 1 MB
  u16* w1t  = (u16*)p; p += (size_t)8 * 512 * 1024 * 2;// 8 MB
  u16* w2t  = (u16*)p; p += (size_t)8 * 64 * 512 * 2;  // 0.5 MB
  int* list = (int*)p; p += (size_t)8192 * 4;          // 32 KB
  int* off  = (int*)p; p += 64;
  int* cnts = (int*)p; p += 64 * 8 * 4;

  // D1: W_in transpose + routing histogram (only true L1 prerequisites)
  wsmall<<<192, 256, 0, stream>>>(W_in, cat, wtin, cnts);

  // D2: L1 gemm (x consumed as f32 directly) + scatter (y==8) + W1/W2 converts (y>=9)
  gemm_t<1, 128, 512, 1024><<<dim3(128, 18), 256, 0, stream>>>(
      x, nullptr, wtin, b_in, nullptr, nullptr, midb, nullptr,
      cat, cnts, list, off, W1, W2, w1t, w2t);

  // D3: L2 grouped  [cnt_e,1024] @ [1024,512] -> hb (compact)
  gemm_t<2, 128, 1024, 512><<<dim3(136, 4), 256, 0, stream>>>(
      nullptr, midb, w1t, b1, list, off, hb, nullptr,
      nullptr, nullptr, nullptr, nullptr, nullptr, nullptr, nullptr, nullptr);

  // D4: L3 grouped  [cnt_e,512] @ [512,64] -> out (scattered)
  gemm_t<3, 64, 512, 64><<<dim3(136, 1), 256, 0, stream>>>(
      nullptr, hb, w2t, b2, list, off, nullptr, out,
      nullptr, nullptr, nullptr, nullptr, nullptr, nullptr, nullptr, nullptr);
}

// Round 11
// 64.328 us; speedup vs baseline: 4.4204x; 1.0387x over previous
//
#include <hip/hip_runtime.h>

typedef unsigned short u16;
typedef unsigned int u32;
typedef __bf16 bf16x8 __attribute__((ext_vector_type(8)));
typedef float f32x4 __attribute__((ext_vector_type(4)));

#define GLD_LDS(gptr, lptr) \
  __builtin_amdgcn_global_load_lds((const __attribute__((address_space(1))) void*)(gptr), \
                                   (__attribute__((address_space(3))) void*)(lptr), 16, 0, 0)

__device__ __forceinline__ u16 f2b(float f) {
  union { __bf16 h; u16 u; } v; v.h = (__bf16)f; return v.u;
}
__device__ __forceinline__ float elu1(float v) {
  return v > 0.f ? v : (__expf(v) - 1.f);
}

// ---------------- 64x64 transpose-convert tile (f32 [R][C] -> bf16 [C][R]) ----------------
__device__ void transpose_tile(float (*tbuf)[65], const float* __restrict__ src,
                               u16* __restrict__ dst, int R, int C, int tr, int tc,
                               size_t zoff) {
  const int tid = threadIdx.x;
  const float* sp = src + zoff + (size_t)(tr * 64) * C + tc * 64;
#pragma unroll
  for (int i = 0; i < 4; i++) {
    const int rr = (tid >> 4) + i * 16, f = tid & 15;
    float4 v = *reinterpret_cast<const float4*>(sp + (size_t)rr * C + f * 4);
    tbuf[rr][f * 4 + 0] = v.x; tbuf[rr][f * 4 + 1] = v.y;
    tbuf[rr][f * 4 + 2] = v.z; tbuf[rr][f * 4 + 3] = v.w;
  }
  __syncthreads();
  u16* dp = dst + zoff + (size_t)(tc * 64) * R + tr * 64;
#pragma unroll
  for (int i = 0; i < 4; i++) {
    const int u = tid + i * 256;
    const int c = u >> 4, rq = u & 15;
    ushort4 w;
    w.x = f2b(tbuf[rq * 4 + 0][c]); w.y = f2b(tbuf[rq * 4 + 1][c]);
    w.z = f2b(tbuf[rq * 4 + 2][c]); w.w = f2b(tbuf[rq * 4 + 3][c]);
    *reinterpret_cast<ushort4*>(dp + (size_t)c * R + rq * 4) = w;
  }
}

// ---------------- routing, stage 1: per-chunk histogram (64 chunks x 128 samples) ----------
__device__ void hist_body(int rb, const int* __restrict__ cat, int* __restrict__ cnts) {
  __shared__ int c8[8];
  const int tid = threadIdx.x;
  if (tid < 8) c8[tid] = 0;
  __syncthreads();
  if (tid < 128) atomicAdd(&c8[cat[rb * 128 + tid]], 1);
  __syncthreads();
  if (tid < 8) cnts[rb * 8 + tid] = c8[tid];
}

// ---------------- routing, stage 2: independent prefix + scatter -------------------------
__device__ void scatter_body(int rb, const int* __restrict__ cat,
                             const int* __restrict__ cnts,
                             int* __restrict__ list, int* __restrict__ off) {
  __shared__ int lc[512];       // cnts[64][8]
  __shared__ int lcur[8];
  __shared__ int starts[8];
  const int tid = threadIdx.x;
  lc[tid] = cnts[tid];
  lc[tid + 256] = cnts[tid + 256];
  if (tid < 8) lcur[tid] = 0;
  __syncthreads();
  if (tid < 8) {
    const int c = tid;
    int base = 0;
    for (int cc = 0; cc < c; cc++) {
      int s = 0;
      for (int b = 0; b < 64; b++) s += lc[b * 8 + cc];
      base += s;
    }
    int pre = 0;
    for (int b = 0; b < rb; b++) pre += lc[b * 8 + c];
    starts[c] = base + pre;
    if (rb == 0) {
      off[c] = base;
      if (c == 7) {
        int s = 0;
        for (int b = 0; b < 64; b++) s += lc[b * 8 + 7];
        off[8] = base + s;
      }
    }
  }
  __syncthreads();
  if (tid < 128) {
    const int idx = rb * 128 + tid;
    const int c = cat[idx];
    const int r = atomicAdd(&lcur[c], 1);
    list[starts[c] + r] = idx;
  }
}

// ---------------- small front kernel: W_in transpose + routing histogram -------------------
__global__ __launch_bounds__(256) void wsmall(const float* __restrict__ W_in,
                                              const int* __restrict__ cat,
                                              u16* __restrict__ o0, int* __restrict__ cnts) {
  __shared__ float tbuf[64][65];
  if (blockIdx.x >= 128) { hist_body(blockIdx.x - 128, cat, cnts); return; }
  transpose_tile(tbuf, W_in, o0, 512, 1024, blockIdx.x >> 4, blockIdx.x & 15, 0);
}

// ---------------- unified pipelined GEMM (R3-proven loop) + T1 XCD-chunked swizzle ---------
// LAYER 1: A = x (f32, reg-staged inline cvt), riders: y==8 scatter, y==9..16 W1, y==17 W2.
// LAYER 2: rows gathered via list, compact bf16 out + ELU.
// LAYER 3: compact rows, f32 out scattered via list, no activation.

template<int LAYER, int BN, int K, int N>
__global__ __launch_bounds__(256, 4) void gemm_t(
    const float* __restrict__ Xf, const u16* __restrict__ A,
    const u16* __restrict__ Bw, const float* __restrict__ bias,
    const int* __restrict__ list, const int* __restrict__ off,
    u16* __restrict__ outb, float* __restrict__ outf,
    const int* __restrict__ cat, const int* __restrict__ cnts,
    int* __restrict__ wlist, int* __restrict__ woff,
    const float* __restrict__ Wc1, const float* __restrict__ Wc2,
    u16* __restrict__ o1, u16* __restrict__ o2) {
  struct GBuf { alignas(16) u16 As[2][2048]; alignas(16) u16 Bs[2][BN * 32]; };
  __shared__ union SM { GBuf g; float tbuf[64][65]; } sm;

  const int tid = threadIdx.x;

  if constexpr (LAYER == 1) {
    if (blockIdx.y == 8) {                 // routing scatter (raw index)
      if (blockIdx.x < 64) scatter_body(blockIdx.x, cat, cnts, wlist, woff);
      return;
    }
    if (blockIdx.y >= 9) {                 // weight converts (raw index)
      if (blockIdx.y <= 16) {
        const int t = (blockIdx.y - 9) * 128 + blockIdx.x;   // 0..1023
        const int z = t >> 7, rem = t & 127;
        transpose_tile(sm.tbuf, Wc1, o1, 1024, 512, rem >> 3, rem & 7,
                       (size_t)z * 1024 * 512);
      } else if (blockIdx.x < 64) {
        const int t = blockIdx.x, z = t >> 3;
        transpose_tile(sm.tbuf, Wc2, o2, 512, 64, t & 7, 0, (size_t)z * 512 * 64);
      }
      return;
    }
  }

  // ---- T1: XCD-chunked bijective block swizzle (dispatch order = x fastest, RR over XCDs) ----
  int tidx, col0;
  if constexpr (LAYER == 1) {
    const int orig = blockIdx.y * 128 + blockIdx.x;     // 0..1023 (y<8 here)
    const int work = (orig & 7) * 128 + (orig >> 3);    // 1024/8 = 128 per XCD
    tidx = work >> 3;                                   // row tile 0..127
    col0 = (work & 7) * BN;
  } else if constexpr (LAYER == 2) {
    const int orig = blockIdx.y * 136 + blockIdx.x;     // 0..543
    const int work = (orig & 7) * 68 + (orig >> 3);     // 544/8 = 68 per XCD
    tidx = work >> 2;                                   // grouped tile 0..135
    col0 = (work & 3) * BN;
  } else {
    const int orig = blockIdx.x;                        // 0..135
    const int work = (orig & 7) * 17 + (orig >> 3);     // 136/8 = 17 per XCD
    tidx = work;
    col0 = 0;
  }

  const int wave = tid >> 6, lane = tid & 63;

  int e = 0, start = 0, cnt = 0, rowbase;
  if constexpr (LAYER == 1) {
    rowbase = tidx * 64;
  } else {
    int t = tidx;
    int found = -1;
    for (e = 0; e < 8; e++) {
      int tiles = (off[e + 1] - off[e] + 63) >> 6;
      if (t < tiles) { found = e; break; }
      t -= tiles;
    }
    if (found < 0) return;
    start = off[e];
    cnt = off[e + 1] - start;
    rowbase = t * 64;
  }

  const int srow = tid >> 2, skc = tid & 3;
  const int kxs = (skc ^ (srow & 3)) * 8;

  const float* ax = nullptr;
  const u16* a_src = nullptr;
  if constexpr (LAYER == 1) {
    ax = Xf + (size_t)(rowbase + srow) * K + kxs;
  } else if constexpr (LAYER == 2) {
    int gr = list[start + min(rowbase + srow, cnt - 1)];
    a_src = A + (size_t)gr * K + kxs;
  } else {
    a_src = A + (size_t)(start + min(rowbase + srow, cnt - 1)) * K + kxs;
  }
  const u16* Bbase = Bw + (LAYER == 1 ? (size_t)0 : (size_t)e * N * K);
  const u16* b_src0 = Bbase + (size_t)(col0 + srow) * K + kxs;
  const u16* b_src1 = Bbase + (size_t)(col0 + 64 + srow) * K + kxs;

  const int wbase = wave * 512;

  constexpr int NR = BN / 32;
  const int wy = wave & 1, wx = wave >> 1;
  const int fr = lane & 15, kg = lane >> 4;
  const int kx = (kg ^ (fr & 3)) * 8;
  const int ar0 = (wy * 32 + fr) * 32 + kx;
  const int br0 = (wx * (BN / 2) + fr) * 32 + kx;

  f32x4 acc[2][NR] = {};

  float4 va0, va1;                          // L1 in-flight A (f32)
  auto LOAD_A1 = [&](int t) {
    va0 = *reinterpret_cast<const float4*>(ax + t * 32);
    va1 = *reinterpret_cast<const float4*>(ax + t * 32 + 4);
  };
  auto WRITE_A1 = [&](int buf) {
    uint4 w;
    w.x = (u32)f2b(va0.x) | ((u32)f2b(va0.y) << 16);
    w.y = (u32)f2b(va0.z) | ((u32)f2b(va0.w) << 16);
    w.z = (u32)f2b(va1.x) | ((u32)f2b(va1.y) << 16);
    w.w = (u32)f2b(va1.z) | ((u32)f2b(va1.w) << 16);
    *reinterpret_cast<uint4*>(&sm.g.As[buf][srow * 32 + skc * 8]) = w;
  };
  auto COMPUTE = [&](int buf) {
    bf16x8 af[2], bfv[NR];
#pragma unroll
    for (int m = 0; m < 2; m++) af[m] = *(const bf16x8*)&sm.g.As[buf][ar0 + m * 16 * 32];
#pragma unroll
    for (int n = 0; n < NR; n++) bfv[n] = *(const bf16x8*)&sm.g.Bs[buf][br0 + n * 16 * 32];
#pragma unroll
    for (int m = 0; m < 2; m++)
#pragma unroll
      for (int n = 0; n < NR; n++)
        acc[m][n] = __builtin_amdgcn_mfma_f32_16x16x32_bf16(af[m], bfv[n], acc[m][n], 0, 0, 0);
  };

  constexpr int NK = K / 32;
  if constexpr (LAYER == 1) LOAD_A1(0);
  else GLD_LDS(a_src, &sm.g.As[0][wbase]);
  GLD_LDS(b_src0, &sm.g.Bs[0][wbase]);
  if constexpr (BN == 128) GLD_LDS(b_src1, &sm.g.Bs[0][2048 + wbase]);
  if constexpr (LAYER == 1) WRITE_A1(0);
  __syncthreads();

  for (int it = 0; it < NK; ++it) {
    const int cur = it & 1;
    const int nxt = cur ^ 1;
    if (it + 1 < NK) {
      const int kt = (it + 1) * 32;
      if constexpr (LAYER == 1) LOAD_A1(it + 1);
      else GLD_LDS(a_src + kt, &sm.g.As[nxt][wbase]);
      GLD_LDS(b_src0 + kt, &sm.g.Bs[nxt][wbase]);
      if constexpr (BN == 128) GLD_LDS(b_src1 + kt, &sm.g.Bs[nxt][2048 + wbase]);
    }
    COMPUTE(cur);
    if constexpr (LAYER == 1) { if (it + 1 < NK) WRITE_A1(nxt); }
    __syncthreads();
  }

#pragma unroll
  for (int n = 0; n < NR; n++) {
    const int col = col0 + wx * (BN / 2) + n * 16 + fr;
    const float bc = bias[(LAYER == 1 ? 0 : e * N) + col];
#pragma unroll
    for (int m = 0; m < 2; m++) {
      const int rloc = wy * 32 + m * 16 + kg * 4;
#pragma unroll
      for (int j = 0; j < 4; j++) {
        const float v = acc[m][n][j] + bc;
        if constexpr (LAYER == 1) {
          outb[(size_t)(rowbase + rloc + j) * N + col] = f2b(elu1(v));
        } else if constexpr (LAYER == 2) {
          const int slot = rowbase + rloc + j;
          if (slot < cnt) outb[(size_t)(start + slot) * N + col] = f2b(elu1(v));
        } else {
          const int slot = rowbase + rloc + j;
          if (slot < cnt) outf[(size_t)list[start + slot] * N + col] = v;
        }
      }
    }
  }
}

// ---------------- launch ----------------

extern "C" void kernel_launch(void* const* d_in, const int* in_sizes, int n_in,
                              void* d_out, int out_size, void* d_ws, size_t ws_size,
                              hipStream_t stream) {
  const float* x    = (const float*)d_in[0];
  const int*   cat  = (const int*)d_in[1];
  const float* W_in = (const float*)d_in[2];
  const float* b_in = (const float*)d_in[3];
  const float* W1   = (const float*)d_in[4];
  const float* b1   = (const float*)d_in[5];
  const float* W2   = (const float*)d_in[6];
  const float* b2   = (const float*)d_in[7];
  float* out = (float*)d_out;

  char* p = (char*)d_ws;
  u16* midb = (u16*)p; p += (size_t)8192 * 1024 * 2;   // 16 MB
  u16* hb   = (u16*)p; p += (size_t)8192 * 512 * 2;    // 8 MB
  u16* wtin = (u16*)p; p += (size_t)1024 * 512 * 2;    // 1 MB
  u16* w1t  = (u16*)p; p += (size_t)8 * 512 * 1024 * 2;// 8 MB
  u16* w2t  = (u16*)p; p += (size_t)8 * 64 * 512 * 2;  // 0.5 MB
  int* list = (int*)p; p += (size_t)8192 * 4;          // 32 KB
  int* off  = (int*)p; p += 64;
  int* cnts = (int*)p; p += 64 * 8 * 4;

  // D1: W_in transpose + routing histogram
  wsmall<<<192, 256, 0, stream>>>(W_in, cat, wtin, cnts);

  // D2: L1 gemm (x as f32) + scatter (y==8) + W1/W2 converts (y>=9)
  gemm_t<1, 128, 512, 1024><<<dim3(128, 18), 256, 0, stream>>>(
      x, nullptr, wtin, b_in, nullptr, nullptr, midb, nullptr,
      cat, cnts, list, off, W1, W2, w1t, w2t);

  // D3: L2 grouped  [cnt_e,1024] @ [1024,512] -> hb (compact)
  gemm_t<2, 128, 1024, 512><<<dim3(136, 4), 256, 0, stream>>>(
      nullptr, midb, w1t, b1, list, off, hb, nullptr,
      nullptr, nullptr, nullptr, nullptr, nullptr, nullptr, nullptr, nullptr);

  // D4: L3 grouped  [cnt_e,512] @ [512,64] -> out (scattered)
  gemm_t<3, 64, 512, 64><<<dim3(136, 1), 256, 0, stream>>>(
      nullptr, hb, w2t, b2, list, off, nullptr, out,
      nullptr, nullptr, nullptr, nullptr, nullptr, nullptr, nullptr, nullptr);
}